// Round 1
// 216.269 us; speedup vs baseline: 1.0127x; 1.0127x over previous
//
#include <hip/hip_runtime.h>

// RNN_arch_2: 16-step vanilla RNN, B=16384, D_IN=64, D_H=256, D_MID=64, D_OUT=4.
// R3: barrier/latency-bound restructure (was 48 barriers, 3/step):
//  - h double-buffered in LDS -> ONE barrier per iteration (18 total).
//  - fused phase: pre-GEMM for h_{t+1} + h2o(h_t) share the same h-fragments.
//  - x_{t+1} prefetched via global_load_lds into swizzled-linear LDS (latency
//    hidden under the 96-MFMA phase; barrier drain guarantees arrival).
//  - MFMA operands swapped (W as A-operand) so the tanh epilogue writes
//    4xf16 ds_write_b64 instead of 32 scattered ds_write_b16.
//  - fc split-K over all 256 threads, issued before MFMA so stores drain.
// Weights persist in registers (192 regs -> 2 blocks/CU cap stands).

typedef _Float16 half8 __attribute__((ext_vector_type(8)));
typedef _Float16 half4 __attribute__((ext_vector_type(4)));
typedef float floatx4 __attribute__((ext_vector_type(4)));

#define T_STEPS  16
#define BATCH    16384
#define BLK_ROWS 32
#define HS       264   // h_lds row stride (f16): 528B -> balanced b128 reads
#define MS       72    // mid_lds row stride (f16)

#define AS1C(p) ((const __attribute__((address_space(1))) unsigned int*)(p))
#define AS3(p)  ((__attribute__((address_space(3))) unsigned int*)(p))

__device__ inline float fast_tanh(float x) {
    // tanh(x) = 1 - 2/(1+exp2(2*log2e*x)); saturates correctly at +-inf
    float t = __builtin_amdgcn_exp2f(x * 2.8853900817779268f);
    return 1.0f - 2.0f * __builtin_amdgcn_rcpf(t + 1.0f);
}

__device__ inline half8 pack8(float4 a, float4 b) {
    half8 h;
    h[0] = (_Float16)a.x; h[1] = (_Float16)a.y; h[2] = (_Float16)a.z; h[3] = (_Float16)a.w;
    h[4] = (_Float16)b.x; h[5] = (_Float16)b.y; h[6] = (_Float16)b.z; h[7] = (_Float16)b.w;
    return h;
}

__device__ inline half8 cvt8(const float* __restrict__ p) {
    return pack8(((const float4*)p)[0], ((const float4*)p)[1]);
}

// Fused MFMA phase. Operand-swapped: mfma(a=W[idx][k], b=act[batch][k]) gives
// C[row = weight-dim (quad*4+r)][col = batch (l16)].
template<int DO_PRE, int DO_MID>
__device__ __forceinline__ void mfma_phase(
    const _Float16* __restrict__ hcur, const float* __restrict__ xcur,
    const half8 (&wcat)[10][4], const half8 (&wof)[8],
    floatx4 (&acc)[2][4], floatx4 (&ac2)[2], int l16, int quad)
{
    // h-part (K slices 2..9 of pre) + h2o share the same h fragments
    #pragma unroll
    for (int ks2 = 0; ks2 < 8; ++ks2) {
        half8 hf[2];
        #pragma unroll
        for (int mt = 0; mt < 2; ++mt)
            hf[mt] = *(const half8*)&hcur[(mt * 16 + l16) * HS + ks2 * 32 + quad * 8];
        if (DO_PRE) {
            #pragma unroll
            for (int mt = 0; mt < 2; ++mt)
                #pragma unroll
                for (int nt = 0; nt < 4; ++nt)
                    acc[mt][nt] = __builtin_amdgcn_mfma_f32_16x16x32_f16(
                        wcat[ks2 + 2][nt], hf[mt], acc[mt][nt], 0, 0, 0);
        }
        if (DO_MID) {
            #pragma unroll
            for (int mt = 0; mt < 2; ++mt)
                ac2[mt] = __builtin_amdgcn_mfma_f32_16x16x32_f16(
                    wof[ks2], hf[mt], ac2[mt], 0, 0, 0);
        }
    }
    // x-part (K slices 0..1), fragments from swizzled x_lds (f32)
    if (DO_PRE) {
        #pragma unroll
        for (int k2 = 0; k2 < 2; ++k2) {
            half8 af[2];
            #pragma unroll
            for (int mt = 0; mt < 2; ++mt) {
                int row = mt * 16 + l16, sw = row & 7;
                int ub = row * 16 + k2 * 8 + quad * 2;
                float4 a = *(const float4*)&xcur[(ub ^ sw) * 4];
                float4 b = *(const float4*)&xcur[((ub + 1) ^ sw) * 4];
                af[mt] = pack8(a, b);
            }
            #pragma unroll
            for (int mt = 0; mt < 2; ++mt)
                #pragma unroll
                for (int nt = 0; nt < 4; ++nt)
                    acc[mt][nt] = __builtin_amdgcn_mfma_f32_16x16x32_f16(
                        wcat[k2][nt], af[mt], acc[mt][nt], 0, 0, 0);
        }
    }
}

// h = tanh(pre + bias) -> h_lds[nxt]; C row = hidden-dim -> 4 consecutive f16
__device__ __forceinline__ void epi_h(_Float16* __restrict__ hnxt,
                                      const floatx4 (&acc)[2][4],
                                      const float* __restrict__ biasPre,
                                      int w, int l16, int quad)
{
    #pragma unroll
    for (int nt = 0; nt < 4; ++nt) {
        int hb = w * 64 + nt * 16 + quad * 4;
        float4 bias = *(const float4*)&biasPre[hb];
        #pragma unroll
        for (int mt = 0; mt < 2; ++mt) {
            int mb = mt * 16 + l16;
            half4 v;
            v[0] = (_Float16)fast_tanh(acc[mt][nt][0] + bias.x);
            v[1] = (_Float16)fast_tanh(acc[mt][nt][1] + bias.y);
            v[2] = (_Float16)fast_tanh(acc[mt][nt][2] + bias.z);
            v[3] = (_Float16)fast_tanh(acc[mt][nt][3] + bias.w);
            *(half4*)&hnxt[mb * HS + hb] = v;
        }
    }
}

__device__ __forceinline__ void epi_mid(_Float16* __restrict__ midp,
                                        const floatx4 (&ac2)[2],
                                        const float* __restrict__ bo_lds,
                                        int w, int l16, int quad)
{
    int md = w * 16 + quad * 4;
    float4 bo4 = *(const float4*)&bo_lds[md];
    #pragma unroll
    for (int mt = 0; mt < 2; ++mt) {
        int mb = mt * 16 + l16;
        half4 v;
        v[0] = (_Float16)fast_tanh(ac2[mt][0] + bo4.x);
        v[1] = (_Float16)fast_tanh(ac2[mt][1] + bo4.y);
        v[2] = (_Float16)fast_tanh(ac2[mt][2] + bo4.z);
        v[3] = (_Float16)fast_tanh(ac2[mt][3] + bo4.w);
        *(half4*)&midp[mb * MS + md] = v;
    }
}

// out = mid @ Wfc^T + bfc : 256 threads, split-K pairs combined via shfl_xor
__device__ __forceinline__ void fc_out(const _Float16* __restrict__ midp,
                                       const _Float16* __restrict__ wfc,
                                       const float* __restrict__ bfc,
                                       float* __restrict__ outp,
                                       int ti, int b0, int tid)
{
    const int row = tid >> 3, oc = (tid >> 1) & 3, kh = tid & 1;
    float s = 0.f;
    #pragma unroll
    for (int k8 = 0; k8 < 32; k8 += 8) {
        half8 mv = *(const half8*)&midp[row * MS + kh * 32 + k8];
        half8 wv = *(const half8*)&wfc[oc * 64 + kh * 32 + k8];
        #pragma unroll
        for (int j = 0; j < 8; ++j) s += (float)mv[j] * (float)wv[j];
    }
    s += __shfl_xor(s, 1, 64);
    if (kh == 0)
        outp[((size_t)ti * BATCH + b0 + row) * 4 + oc] = s + bfc[oc];
}

__global__ __launch_bounds__(256, 2) void rnn_kernel(
    const float* __restrict__ x,   const float* __restrict__ hc1,
    const float* __restrict__ Wi,  const float* __restrict__ bi,
    const float* __restrict__ Wh,  const float* __restrict__ bh,
    const float* __restrict__ Wo,  const float* __restrict__ bo,
    const float* __restrict__ Wf,  const float* __restrict__ bf,
    float* __restrict__ out)
{
    __shared__ _Float16 h_lds[2][BLK_ROWS * HS];    // double-buffered h (f16)
    __shared__ float    x_lds[2][BLK_ROWS * 64];    // prefetched x tile (f32, swizzled)
    __shared__ _Float16 mid_lds[2][BLK_ROWS * MS];  // double-buffered mid
    __shared__ float    biasPre[256];               // b_i2h + b_h2h
    __shared__ float    bo_lds[64];
    __shared__ _Float16 wfc_lds[4 * 64];
    __shared__ float    bfc_lds[4];

    const int tid  = threadIdx.x;
    const int w    = tid >> 6;
    const int lane = tid & 63;
    const int l16  = lane & 15;
    const int quad = lane >> 4;
    const int b0   = blockIdx.x * BLK_ROWS;

    // x staging: 512 16B-units/tile; LDS unit u' holds global unit u'^((u'>>4)&7)
    const int g0 = tid ^ ((tid >> 4) & 7);
    const int u1 = 256 + tid;
    const int g1 = u1 ^ ((u1 >> 4) & 7);

#define PREFETCH_X(ti, xb) do {                                                        \
        const float* xsrc_ = x + ((size_t)(ti) * BATCH + b0) * 64;                     \
        __builtin_amdgcn_global_load_lds(AS1C(xsrc_ + (size_t)g0 * 4),                 \
                                         AS3(&x_lds[xb][w * 256]), 16, 0, 0);          \
        __builtin_amdgcn_global_load_lds(AS1C(xsrc_ + (size_t)g1 * 4),                 \
                                         AS3(&x_lds[xb][1024 + w * 256]), 16, 0, 0);   \
    } while (0)

#define ZERO_ACC() do {                                                                \
        _Pragma("unroll")                                                              \
        for (int mt = 0; mt < 2; ++mt) {                                               \
            ac2[mt] = (floatx4){0.f, 0.f, 0.f, 0.f};                                   \
            _Pragma("unroll")                                                          \
            for (int nt = 0; nt < 4; ++nt) acc[mt][nt] = (floatx4){0.f, 0.f, 0.f, 0.f};\
        }                                                                              \
    } while (0)

    PREFETCH_X(0, 0);   // x_0 in flight under the whole prologue

    // --- one-time LDS init ---
    biasPre[tid] = bi[tid] + bh[tid];
    if (tid < 64) bo_lds[tid] = bo[tid];
    wfc_lds[tid] = (_Float16)Wf[tid];
    if (tid < 4) bfc_lds[tid] = bf[tid];

    // stage hc1 -> h_lds[0]
    {
        const int r = tid >> 3, c0 = (tid & 7) * 32;
        const float4* src = (const float4*)&hc1[(size_t)(b0 + r) * 256 + c0];
        #pragma unroll
        for (int i2 = 0; i2 < 8; ++i2) {
            float4 v = src[i2];
            half4 hv;
            hv[0] = (_Float16)v.x; hv[1] = (_Float16)v.y;
            hv[2] = (_Float16)v.z; hv[3] = (_Float16)v.w;
            *(half4*)&h_lds[0][r * HS + c0 + i2 * 4] = hv;
        }
    }

    // --- persistent weight fragments (registers, loaded once) ---
    half8 wcat[10][4];   // K=320 concat [Wi(k<64); Wh], 4 n-tiles/wave
    #pragma unroll
    for (int ks = 0; ks < 10; ++ks)
        #pragma unroll
        for (int nt = 0; nt < 4; ++nt) {
            int j = w * 64 + nt * 16 + l16;
            const float* src = (ks < 2)
                ? (Wi + (size_t)j * 64  + ks * 32 + quad * 8)
                : (Wh + (size_t)j * 256 + (ks - 2) * 32 + quad * 8);
            wcat[ks][nt] = cvt8(src);
        }
    half8 wof[8];        // W_h2o: wave covers 16 mid-dims, K=256
    #pragma unroll
    for (int ks = 0; ks < 8; ++ks)
        wof[ks] = cvt8(Wo + (size_t)(w * 16 + l16) * 256 + ks * 32 + quad * 8);

    __syncthreads();

    // ---- i = 0 : pre only ----
    {
        PREFETCH_X(1, 1);
        floatx4 acc[2][4], ac2[2];
        ZERO_ACC();
        mfma_phase<1, 0>(h_lds[0], x_lds[0], wcat, wof, acc, ac2, l16, quad);
        epi_h(h_lds[1], acc, biasPre, w, l16, quad);
        __syncthreads();
    }

    // ---- main loop: i = 1..15, ONE barrier each ----
    #pragma unroll 1
    for (int i = 1; i <= 15; ++i) {
        const int cur = i & 1, nxt = cur ^ 1;
        if (i < 15) PREFETCH_X(i + 1, nxt);
        if (i >= 2) fc_out(mid_lds[nxt], wfc_lds, bfc_lds, out, i - 2, b0, tid);
        floatx4 acc[2][4], ac2[2];
        ZERO_ACC();
        mfma_phase<1, 1>(h_lds[cur], x_lds[cur], wcat, wof, acc, ac2, l16, quad);
        epi_h(h_lds[nxt], acc, biasPre, w, l16, quad);
        epi_mid(mid_lds[cur], ac2, bo_lds, w, l16, quad);
        __syncthreads();
    }

    // ---- i = 16 : h2o(h_16) + drain fc ----
    {
        fc_out(mid_lds[1], wfc_lds, bfc_lds, out, 14, b0, tid);
        floatx4 acc[2][4], ac2[2];
        ZERO_ACC();
        mfma_phase<0, 1>(h_lds[0], x_lds[0], wcat, wof, acc, ac2, l16, quad);
        epi_mid(mid_lds[0], ac2, bo_lds, w, l16, quad);
        __syncthreads();
        fc_out(mid_lds[0], wfc_lds, bfc_lds, out, 15, b0, tid);
    }

    // ---- h_final (fp32) at offset T*B*4, from h_lds[0] ----
    {
        const int r = tid >> 3, c0 = (tid & 7) * 32;
        float4* dst = (float4*)&out[(size_t)T_STEPS * BATCH * 4 + (size_t)(b0 + r) * 256 + c0];
        #pragma unroll
        for (int i2 = 0; i2 < 8; ++i2) {
            int c = c0 + i2 * 4;
            float4 v;
            v.x = (float)h_lds[0][r * HS + c + 0];
            v.y = (float)h_lds[0][r * HS + c + 1];
            v.z = (float)h_lds[0][r * HS + c + 2];
            v.w = (float)h_lds[0][r * HS + c + 3];
            dst[i2] = v;
        }
    }
#undef PREFETCH_X
#undef ZERO_ACC
}

extern "C" void kernel_launch(void* const* d_in, const int* in_sizes, int n_in,
                              void* d_out, int out_size, void* d_ws, size_t ws_size,
                              hipStream_t stream) {
    const float* x   = (const float*)d_in[0];
    const float* hc1 = (const float*)d_in[1];
    const float* Wi  = (const float*)d_in[2];
    const float* bi  = (const float*)d_in[3];
    const float* Wh  = (const float*)d_in[4];
    const float* bh  = (const float*)d_in[5];
    const float* Wo  = (const float*)d_in[6];
    const float* bo  = (const float*)d_in[7];
    const float* Wf  = (const float*)d_in[8];
    const float* bf  = (const float*)d_in[9];

    rnn_kernel<<<BATCH / BLK_ROWS, 256, 0, stream>>>(
        x, hc1, Wi, bi, Wh, bh, Wo, bo, Wf, bf, (float*)d_out);
}